// Round 6
// baseline (809.416 us; speedup 1.0000x reference)
//
#include <hip/hip_runtime.h>
#include <cstdint>
#include <cstddef>

typedef unsigned short u16;
typedef short s8v __attribute__((ext_vector_type(8)));
typedef float f4v __attribute__((ext_vector_type(4)));

#define DEV static __device__ __forceinline__

DEV float bf2f(u16 u) {
  union { unsigned int i; float f; } v; v.i = ((unsigned int)u) << 16; return v.f;
}
DEV u16 f2bf(float f) {
  union { unsigned int i; float f; } v; v.f = f;
  unsigned int r = v.i + 0x7fffu + ((v.i >> 16) & 1u);
  return (u16)(r >> 16);
}

DEV void load_lds16(const u16* g, u16* l) {
  __builtin_amdgcn_global_load_lds((const __attribute__((address_space(1))) void*)g,
                                   (__attribute__((address_space(3))) void*)l, 16, 0, 0);
}

DEV f4v mfma16(s8v a, s8v b, f4v c) {
  return __builtin_amdgcn_mfma_f32_16x16x32_bf16(a, b, c, 0, 0, 0);
}

// ---------------------------------------------------------------------------
// fused fp32 -> bf16 convert for all 5 inputs (dst segments contiguous in ws:
// xb | wqb | wkb | wvb | wob). One dispatch replaces five.
// ---------------------------------------------------------------------------
__global__ __launch_bounds__(256)
void cvt_all(const float* __restrict__ x,  const float* __restrict__ wq,
             const float* __restrict__ wk, const float* __restrict__ wv,
             const float* __restrict__ wo, u16* __restrict__ dst)
{
  const size_t NB = (size_t)4096 * 4096;
  const size_t KV = (size_t)4096 * 1024;
  const size_t gi = ((size_t)blockIdx.x * 256 + threadIdx.x) * 4;
  const float* src;
  size_t li;
  if (gi < NB)                { src = x;  li = gi; }
  else if (gi < 2 * NB)       { src = wq; li = gi - NB; }
  else if (gi < 2 * NB + KV)  { src = wk; li = gi - 2 * NB; }
  else if (gi < 2 * NB + 2*KV){ src = wv; li = gi - 2 * NB - KV; }
  else                        { src = wo; li = gi - 2 * NB - 2 * KV; }
  const float4 v = *(const float4*)(src + li);
  u16 o[4] = { f2bf(v.x), f2bf(v.y), f2bf(v.z), f2bf(v.w) };
  *(ushort4*)(dst + gi) = *(ushort4*)o;
}

DEV void storec(float* p, float v) { *p = v; }
DEV void storec(u16* p, float v)   { *p = f2bf(v); }

// ---------------------------------------------------------------------------
// 256x256 8-phase GEMM (T2 swizzle + T3/T4 counted vmcnt + T5 setprio).
// Verified round 3. C = A[M,K] * Bt[N,K]^T. 512 threads = 8 waves. BK=64.
// ---------------------------------------------------------------------------
#define BARR  __builtin_amdgcn_s_barrier()
#define LGKM0 asm volatile("s_waitcnt lgkmcnt(0)" ::: "memory")
#define WVM4  asm volatile("s_waitcnt vmcnt(4)" ::: "memory")
#define WVM2  asm volatile("s_waitcnt vmcnt(2)" ::: "memory")
#define WVM0  asm volatile("s_waitcnt vmcnt(0)" ::: "memory")
#define MEMF  asm volatile("" ::: "memory")
#define PRIO1 __builtin_amdgcn_s_setprio(1)
#define PRIO0 __builtin_amdgcn_s_setprio(0)

template <typename TC>
__global__ __launch_bounds__(512, 2)
void gemm_256(const u16* __restrict__ A, const u16* __restrict__ Bt,
              TC* __restrict__ C, int M, int N, int K)
{
  __shared__ u16 lA[2][2][8192];
  __shared__ u16 lB[2][2][8192];

  const int tid  = threadIdx.x;
  const int wid  = tid >> 6;
  const int lane = tid & 63;
  const int quad = lane >> 4;
  const int l16  = lane & 15;
  const int wr   = wid >> 2;    // 0..1
  const int wc   = wid & 3;     // 0..3
  const int r0   = blockIdx.y * 256;
  const int c0   = blockIdx.x * 256;

  const int srow = tid >> 3;                                  // 0..63
  const int scol = (((tid & 7) ^ ((tid >> 3) & 7)) << 3);     // u16 units
  const u16* pA = A  + (size_t)(r0 + srow) * K + scol;
  const u16* pB = Bt + (size_t)(c0 + srow) * K + scol;
  const size_t h64  = (size_t)64 * K;
  const size_t h128 = (size_t)128 * K;

  const int swz = (l16 & 7) << 3;
  const int ko0 = (quad * 8) ^ swz;
  const int ko1 = (32 + quad * 8) ^ swz;

  f4v acc[2][2][4][2];
#pragma unroll
  for (int a = 0; a < 2; ++a)
#pragma unroll
    for (int b = 0; b < 2; ++b)
#pragma unroll
      for (int c = 0; c < 4; ++c)
#pragma unroll
        for (int d = 0; d < 2; ++d) acc[a][b][c][d] = (f4v)0.0f;

  s8v af[4][2], b0f[2][2], b1f[2][2];

#define STG_A(BUF, H, K0) do {                                  \
    const u16* g = pA + (size_t)(H) * h128 + (K0);              \
    load_lds16(g,       &lA[BUF][H][wid * 512]);                \
    load_lds16(g + h64, &lA[BUF][H][wid * 512 + 4096]);         \
  } while (0)
#define STG_B(BUF, H, K0) do {                                  \
    const u16* g = pB + (size_t)(H) * h128 + (K0);              \
    load_lds16(g,       &lB[BUF][H][wid * 512]);                \
    load_lds16(g + h64, &lB[BUF][H][wid * 512 + 4096]);         \
  } while (0)

#define RD_A(BUF, MH) do {                                      \
    _Pragma("unroll")                                           \
    for (int mi = 0; mi < 4; ++mi) {                            \
      const int lr = wr * 64 + mi * 16 + l16;                   \
      af[mi][0] = *(const s8v*)&lA[BUF][MH][lr * 64 + ko0];     \
      af[mi][1] = *(const s8v*)&lA[BUF][MH][lr * 64 + ko1];     \
    } } while (0)
#define RD_B(BUF, NH, DST) do {                                 \
    _Pragma("unroll")                                           \
    for (int ni = 0; ni < 2; ++ni) {                            \
      const int lr = wc * 32 + ni * 16 + l16;                   \
      DST[ni][0] = *(const s8v*)&lB[BUF][NH][lr * 64 + ko0];    \
      DST[ni][1] = *(const s8v*)&lB[BUF][NH][lr * 64 + ko1];    \
    } } while (0)

#define MF(MH, NH, BF) do {                                     \
    _Pragma("unroll")                                           \
    for (int mi = 0; mi < 4; ++mi)                              \
      _Pragma("unroll")                                         \
      for (int ni = 0; ni < 2; ++ni) {                          \
        acc[MH][NH][mi][ni] = mfma16(af[mi][0], BF[ni][0], acc[MH][NH][mi][ni]); \
        acc[MH][NH][mi][ni] = mfma16(af[mi][1], BF[ni][1], acc[MH][NH][mi][ni]); \
      } } while (0)

#define TILE(BUF, KN)                                                     \
  RD_A(BUF, 0); RD_B(BUF, 0, b0f); STG_A(BUF ^ 1, 0, KN);                 \
  BARR; LGKM0; PRIO1; MF(0, 0, b0f); PRIO0; WVM4; BARR;                   \
  RD_B(BUF, 1, b1f); STG_B(BUF ^ 1, 0, KN);                               \
  BARR; LGKM0; PRIO1; MF(0, 1, b1f); PRIO0; WVM4; BARR;                   \
  RD_A(BUF, 1); STG_B(BUF ^ 1, 1, KN);                                    \
  BARR; LGKM0; PRIO1; MF(1, 0, b0f); PRIO0; MEMF; BARR;                   \
  STG_A(BUF ^ 1, 1, KN);                                                  \
  BARR; LGKM0; PRIO1; MF(1, 1, b1f); PRIO0; WVM4; BARR;

#define FTILE(BUF)                                                        \
  RD_A(BUF, 0); RD_B(BUF, 0, b0f);                                        \
  BARR; LGKM0; PRIO1; MF(0, 0, b0f); PRIO0; WVM2; BARR;                   \
  RD_B(BUF, 1, b1f);                                                      \
  BARR; LGKM0; PRIO1; MF(0, 1, b1f); PRIO0; WVM0; BARR;                   \
  RD_A(BUF, 1);                                                           \
  BARR; LGKM0; PRIO1; MF(1, 0, b0f); PRIO0; MEMF; BARR;                   \
  PRIO1; MF(1, 1, b1f); PRIO0;

  STG_A(0, 0, 0); STG_B(0, 0, 0); STG_B(0, 1, 0); STG_A(0, 1, 0);
  WVM4; BARR;

  const int NT = K >> 6;
  for (int kt = 0; kt < NT - 2; kt += 2) {
    const int ka = (kt + 1) << 6;
    const int kb = (kt + 2) << 6;
    TILE(0, ka);
    TILE(1, kb);
  }
  TILE(0, (NT - 1) << 6);
  FTILE(1);

#pragma unroll
  for (int mh = 0; mh < 2; ++mh)
#pragma unroll
    for (int nh = 0; nh < 2; ++nh)
#pragma unroll
      for (int mi = 0; mi < 4; ++mi)
#pragma unroll
        for (int ni = 0; ni < 2; ++ni) {
          const int col = c0 + nh * 128 + wc * 32 + ni * 16 + l16;
#pragma unroll
          for (int reg = 0; reg < 4; ++reg) {
            const int row = r0 + mh * 128 + wr * 64 + mi * 16 + quad * 4 + reg;
            storec(&C[(size_t)row * N + col], acc[mh][nh][mi][ni][reg]);
          }
        }
#undef STG_A
#undef STG_B
#undef RD_A
#undef RD_B
#undef MF
#undef TILE
#undef FTILE
}

// ---------------------------------------------------------------------------
// Fused-conversion GEMM (fallback path; verified earlier).
// ---------------------------------------------------------------------------
DEV void stage8(const float* g, u16* dst) {
  const float4 a = *(const float4*)g;
  const float4 b = *(const float4*)(g + 4);
  u16 t[8] = { f2bf(a.x), f2bf(a.y), f2bf(a.z), f2bf(a.w),
               f2bf(b.x), f2bf(b.y), f2bf(b.z), f2bf(b.w) };
  *(s8v*)dst = *(s8v*)t;
}
DEV void stage8(const u16* g, u16* dst) {
  *(s8v*)dst = *(const s8v*)g;
}

template <typename TA, typename TB, typename TC>
__global__ __launch_bounds__(256)
void gemm_bt_f(const TA* __restrict__ A, const TB* __restrict__ Bt,
               TC* __restrict__ C, int M, int N, int K)
{
  __shared__ u16 lds_a[128 * 32];
  __shared__ u16 lds_b[128 * 32];

  const int tid  = threadIdx.x;
  const int w    = tid >> 6;
  const int lane = tid & 63;
  const int quad = lane >> 4;
  const int l16  = lane & 15;
  const int bm   = blockIdx.y;
  const int bn   = blockIdx.x;
  const int wm   = (w >> 1) * 64;
  const int wn   = (w & 1) * 64;

  const int srow = tid >> 2;
  const int scol = (tid & 3) * 8;

  const TA* ga0 = A  + ((size_t)(bm * 128 + srow)) * K + scol;
  const TB* gb0 = Bt + ((size_t)(bn * 128 + srow)) * K + scol;
  const TA* ga1 = ga0 + (size_t)64 * K;
  const TB* gb1 = gb0 + (size_t)64 * K;

  f4v acc[4][4];
#pragma unroll
  for (int i = 0; i < 4; ++i)
#pragma unroll
    for (int j = 0; j < 4; ++j) acc[i][j] = (f4v)0.0f;

  for (int k0 = 0; k0 < K; k0 += 32) {
    stage8(ga0 + k0, &lds_a[tid * 8]);
    stage8(ga1 + k0, &lds_a[2048 + tid * 8]);
    stage8(gb0 + k0, &lds_b[tid * 8]);
    stage8(gb1 + k0, &lds_b[2048 + tid * 8]);
    __syncthreads();

    s8v af[4], bf[4];
#pragma unroll
    for (int mi = 0; mi < 4; ++mi)
      af[mi] = *(const s8v*)&lds_a[(wm + mi * 16 + l16) * 32 + quad * 8];
#pragma unroll
    for (int ni = 0; ni < 4; ++ni)
      bf[ni] = *(const s8v*)&lds_b[(wn + ni * 16 + l16) * 32 + quad * 8];
#pragma unroll
    for (int mi = 0; mi < 4; ++mi)
#pragma unroll
      for (int ni = 0; ni < 4; ++ni)
        acc[mi][ni] = __builtin_amdgcn_mfma_f32_16x16x32_bf16(af[mi], bf[ni], acc[mi][ni], 0, 0, 0);
    __syncthreads();
  }

#pragma unroll
  for (int mi = 0; mi < 4; ++mi)
#pragma unroll
    for (int ni = 0; ni < 4; ++ni) {
      const int col = bn * 128 + wn + ni * 16 + l16;
#pragma unroll
      for (int reg = 0; reg < 4; ++reg) {
        const int row = bm * 128 + wm + mi * 16 + quad * 4 + reg;
        storec(&C[(size_t)row * N + col], acc[mi][ni][reg]);
      }
    }
}

// ---------------------------------------------------------------------------
// RoPE (interleaved pairs), in-place on bf16 buffers; freqs fp32.
// ---------------------------------------------------------------------------
__global__ __launch_bounds__(256)
void rope_kernel(u16* __restrict__ t, const float* __restrict__ cs,
                 const float* __restrict__ sn, int heads, int rowstride)
{
  const int idx = blockIdx.x * 256 + threadIdx.x;
  const int ppr = heads * 64;
  const int row = idx / ppr;
  const int rem = idx - row * ppr;
  const int head = rem >> 6;
  const int pr   = rem & 63;
  const int pos  = row & 2047;
  const float c = cs[pos * 64 + pr];
  const float s = sn[pos * 64 + pr];
  unsigned int* p = (unsigned int*)(t + (size_t)row * rowstride + head * 128 + pr * 2);
  const unsigned int v = *p;
  const float xr = bf2f((u16)(v & 0xffffu));
  const float xi = bf2f((u16)(v >> 16));
  const u16 o0 = f2bf(xr * c - xi * s);
  const u16 o1 = f2bf(xr * s + xi * c);
  *p = (unsigned int)o0 | ((unsigned int)o1 << 16);
}

// ---------------------------------------------------------------------------
// Flash attention: causal, GQA, fixed-max softmax, T14 async-STAGE, LJF,
// setprio. Round 6: swapped QK^T (S^T lane-local in q) + in-register P
// redistribution. FIX vs round 5: the source-register selector (which of
// u[ks*2]/u[ks*2+1] a shfl must deliver) depends on the DEST lane's qh,
// which the source lane cannot see -> shuffle BOTH candidates and select
// with the dest's qh (2 shfl + 1 cndmask per word). No pb LDS buffer.
// Map (re-derived): dest lane (quad,l16) word t of pf[ks] =
//   u[ks*2 + qh_dest][t&1] from lane ((ql_dest*2 + (t>>1))*16 + l16).
// LDS 35.8 KB => 4 blocks/CU. Grid (16, 32, 2), 512 thr = 8 waves x 16 q.
// ---------------------------------------------------------------------------
__global__ __launch_bounds__(512)
void flash_attn128(const u16* __restrict__ xq, const u16* __restrict__ xk,
                   const u16* __restrict__ xv, u16* __restrict__ out, int kvstride)
{
  const int bx  = (int)gridDim.x - 1 - (int)blockIdx.x;  // longest first
  const int h   = blockIdx.y;
  const int b   = blockIdx.z;
  const int kvh = h >> 2;

  const int tid  = threadIdx.x;
  const int w    = tid >> 6;          // 0..7
  const int lane = tid & 63;
  const int quad = lane >> 4;
  const int l16  = lane & 15;

  __shared__ u16 kt[64 * 136];        // K block [kv][d], stride 136
  __shared__ u16 vt[128 * 72];        // V^T block [d][kv], stride 72

  // Q fragments: q-row = bx*128 + w*16 + l16
  const u16* qp = xq + ((size_t)(b * 2048 + bx * 128 + w * 16 + l16)) * 4096 + h * 128 + quad * 8;
  s8v qf[4];
#pragma unroll
  for (int ks = 0; ks < 4; ++ks) qf[ks] = *(const s8v*)(qp + ks * 32);

  f4v oa[8];
#pragma unroll
  for (int i = 0; i < 8; ++i) oa[i] = (f4v)0.0f;
  float l_part = 0.0f;                // per-lane, q = l16 (quad-partial)

  // staging maps (512 threads)
  const int krow = tid >> 3;            // 0..63  (kt row)
  const int kcol = (tid & 7) * 16;      // 0..112 (2 x s8v per thread)
  const int vkv2 = (tid & 31) * 2;      // 0..62  (vt, pair of kv rows)
  const int vdg  = tid >> 5;            // 0..15 -> d group of 8

  const u16* kbase = xk + (size_t)(b * 2048) * kvstride + kvh * 128;
  const u16* vbase = xv + (size_t)(b * 2048) * kvstride + kvh * 128;

  const float scale = 0.08838834764831845f;  // 1/sqrt(128)
  const float MFIX  = 8.0f;                  // fixed softmax shift

  const int nkb   = 2 * bx + 2;              // KV tiles for this q-block
  const int qmaxw = bx * 128 + w * 16 + 15;  // wave's max q-pos (tile skip)
  const int qpos  = bx * 128 + w * 16 + l16; // this lane's q-row
  const int qh    = quad >> 1;
  const int ql    = quad & 1;

  // ---- register prefetch of tile 0 (T14 issue-early)
  s8v kr[2], vr[2];
  {
    const u16* kg = kbase + (size_t)krow * kvstride + kcol;
    kr[0] = *(const s8v*)(kg);
    kr[1] = *(const s8v*)(kg + 8);
    const u16* vg = vbase + (size_t)vkv2 * kvstride + vdg * 8;
    vr[0] = *(const s8v*)(vg);
    vr[1] = *(const s8v*)(vg + kvstride);
  }

  for (int kb = 0; kb < nkb; ++kb) {
    __syncthreads();                  // all waves done reading previous tile
    // ---- write-late: regs -> LDS
    *(s8v*)&kt[krow * 136 + kcol]     = kr[0];
    *(s8v*)&kt[krow * 136 + kcol + 8] = kr[1];
#pragma unroll
    for (int j = 0; j < 8; ++j) {
      const int d = vdg * 8 + j;
      *(unsigned int*)&vt[d * 72 + vkv2] =
          (unsigned int)(u16)vr[0][j] | ((unsigned int)(u16)vr[1][j] << 16);
    }
    // ---- issue-early: next tile's global loads, in flight across compute
    if (kb + 1 < nkb) {
      const u16* kg = kbase + (size_t)((kb + 1) * 64 + krow) * kvstride + kcol;
      kr[0] = *(const s8v*)(kg);
      kr[1] = *(const s8v*)(kg + 8);
      const u16* vg = vbase + (size_t)((kb + 1) * 64 + vkv2) * kvstride + vdg * 8;
      vr[0] = *(const s8v*)(vg);
      vr[1] = *(const s8v*)(vg + kvstride);
    }
    __syncthreads();

    if (kb * 64 <= qmaxw) {           // wave-uniform: skip fully-masked tiles
      // ---- S^T = K Q^T (64kv x 16q per wave): lane holds kv=nb*16+quad*4+reg, q=l16
      f4v sa[4];
#pragma unroll
      for (int nb = 0; nb < 4; ++nb) sa[nb] = (f4v)0.0f;
      __builtin_amdgcn_s_setprio(1);
#pragma unroll
      for (int nb = 0; nb < 4; ++nb)
#pragma unroll
        for (int ks = 0; ks < 4; ++ks) {
          const s8v kf = *(const s8v*)&kt[(nb * 16 + l16) * 136 + ks * 32 + quad * 8];
          sa[nb] = __builtin_amdgcn_mfma_f32_16x16x32_bf16(kf, qf[ks], sa[nb], 0, 0, 0);
        }
      __builtin_amdgcn_s_setprio(0);

      // ---- lane-local softmax numerators; pack pairs to bf16 words
      unsigned int u[4][2];
#pragma unroll
      for (int nb = 0; nb < 4; ++nb)
#pragma unroll
        for (int pair = 0; pair < 2; ++pair) {
          const int kv0 = kb * 64 + nb * 16 + quad * 4 + 2 * pair;
          float p0 = 0.0f, p1 = 0.0f;
          if (kv0 <= qpos)     p0 = __expf(fmaf(sa[nb][2 * pair],     scale, -MFIX));
          if (kv0 + 1 <= qpos) p1 = __expf(fmaf(sa[nb][2 * pair + 1], scale, -MFIX));
          l_part += p0 + p1;
          u[nb][pair] = (unsigned int)f2bf(p0) | ((unsigned int)f2bf(p1) << 16);
        }

      // ---- redistribute: pf[ks] word t = u[ks*2+qh][t&1] from lane
      //      ((ql*2 + (t>>1))*16 + l16). Shuffle both candidates, select by qh.
      s8v pf[2];
#pragma unroll
      for (int ks = 0; ks < 2; ++ks) {
        unsigned int rr[4];
#pragma unroll
        for (int t = 0; t < 4; ++t) {
          const int src = (ql * 2 + (t >> 1)) * 16 + l16;
          const unsigned int va = __shfl(u[ks * 2][t & 1], src);
          const unsigned int vb = __shfl(u[ks * 2 + 1][t & 1], src);
          rr[t] = qh ? vb : va;
        }
        pf[ks] = *(s8v*)rr;
      }

      // ---- O += P V
      __builtin_amdgcn_s_setprio(1);
#pragma unroll
      for (int d8 = 0; d8 < 8; ++d8)
#pragma unroll
        for (int ks = 0; ks < 2; ++ks) {
          const s8v vf = *(const s8v*)&vt[(d8 * 16 + l16) * 72 + ks * 32 + quad * 8];
          oa[d8] = __builtin_amdgcn_mfma_f32_16x16x32_bf16(pf[ks], vf, oa[d8], 0, 0, 0);
        }
      __builtin_amdgcn_s_setprio(0);
    }
  }

  // ---- l: sum quad-partials across the 4 quads holding q=l16, then write
  float l = l_part;
  l += __shfl_xor(l, 16);
  l += __shfl_xor(l, 32);
#pragma unroll
  for (int reg = 0; reg < 4; ++reg) {
    const float inv = 1.0f / __shfl(l, quad * 4 + reg);
    const int row = bx * 128 + w * 16 + quad * 4 + reg;
    u16* op = out + ((size_t)(b * 2048 + row)) * 4096 + h * 128 + l16;
#pragma unroll
    for (int d8 = 0; d8 < 8; ++d8)
      op[d8 * 16] = f2bf(oa[d8][reg] * inv);
  }
}

// ---------------------------------------------------------------------------
extern "C" void kernel_launch(void* const* d_in, const int* in_sizes, int n_in,
                              void* d_out, int out_size, void* d_ws, size_t ws_size,
                              hipStream_t stream)
{
  const float* x  = (const float*)d_in[0];
  const float* fc = (const float*)d_in[2];
  const float* fs = (const float*)d_in[3];
  const float* wq = (const float*)d_in[4];
  const float* wk = (const float*)d_in[5];
  const float* wv = (const float*)d_in[6];
  const float* wo = (const float*)d_in[7];

  const size_t NE_BIG = (size_t)4096 * 4096;
  const size_t NE_KV  = (size_t)4096 * 1024;

  u16* xq = (u16*)d_out;            // Q staged in d_out
  u16* xk = (u16*)d_ws;             // fast path: fused KV [4096][2048]
  u16* xv = xk + NE_KV;             // slow path layout only
  u16* ao = xv + NE_KV;
  u16* xb  = ao + NE_BIG;           // bf16 inputs, contiguous: xb|wqb|wkb|wvb|wob
  u16* wqb = xb  + NE_BIG;
  u16* wkb = wqb + NE_BIG;
  u16* wvb = wkb + NE_KV;
  u16* wob = wvb + NE_KV;

  const size_t need_fast = (size_t)((wob + NE_BIG) - (u16*)d_ws) * sizeof(u16);

  if (ws_size >= need_fast) {
    cvt_all<<<57344, 256, 0, stream>>>(x, wq, wk, wv, wo, xb);
    gemm_256<u16><<<dim3(16, 16), 512, 0, stream>>>(xb, wqb, xq, 4096, 4096, 4096);
    gemm_256<u16><<<dim3(8, 16),  512, 0, stream>>>(xb, wkb, xk, 4096, 2048, 4096);
    rope_kernel<<<32768, 256, 0, stream>>>(xq, fc, fs, 32, 4096);
    rope_kernel<<<8192,  256, 0, stream>>>(xk, fc, fs, 8, 2048);
    flash_attn128<<<dim3(16, 32, 2), 512, 0, stream>>>(xq, xk, xk + 1024, ao, 2048);
    gemm_256<float><<<dim3(16, 16), 512, 0, stream>>>(ao, wob, (float*)d_out, 4096, 4096, 4096);
  } else {
    gemm_bt_f<float, float, u16><<<dim3(32, 32), 256, 0, stream>>>(x, wq, xq, 4096, 4096, 4096);
    gemm_bt_f<float, float, u16><<<dim3(8, 32),  256, 0, stream>>>(x, wk, xk, 4096, 1024, 4096);
    gemm_bt_f<float, float, u16><<<dim3(8, 32),  256, 0, stream>>>(x, wv, xv, 4096, 1024, 4096);
    rope_kernel<<<32768, 256, 0, stream>>>(xq, fc, fs, 32, 4096);
    rope_kernel<<<8192,  256, 0, stream>>>(xk, fc, fs, 8, 1024);
    flash_attn128<<<dim3(16, 32, 2), 512, 0, stream>>>(xq, xk, xv, ao, 1024);
    gemm_bt_f<u16, float, float><<<dim3(32, 32), 256, 0, stream>>>(ao, wo, (float*)d_out, 4096, 4096, 4096);
  }
}

// Round 7
// 784.049 us; speedup vs baseline: 1.0324x; 1.0324x over previous
//
#include <hip/hip_runtime.h>
#include <cstdint>
#include <cstddef>

typedef unsigned short u16;
typedef short s8v __attribute__((ext_vector_type(8)));
typedef float f4v __attribute__((ext_vector_type(4)));

#define DEV static __device__ __forceinline__

DEV float bf2f(u16 u) {
  union { unsigned int i; float f; } v; v.i = ((unsigned int)u) << 16; return v.f;
}
DEV u16 f2bf(float f) {
  union { unsigned int i; float f; } v; v.f = f;
  unsigned int r = v.i + 0x7fffu + ((v.i >> 16) & 1u);
  return (u16)(r >> 16);
}

DEV void load_lds16(const u16* g, u16* l) {
  __builtin_amdgcn_global_load_lds((const __attribute__((address_space(1))) void*)g,
                                   (__attribute__((address_space(3))) void*)l, 16, 0, 0);
}

DEV f4v mfma16(s8v a, s8v b, f4v c) {
  return __builtin_amdgcn_mfma_f32_16x16x32_bf16(a, b, c, 0, 0, 0);
}

// ---------------------------------------------------------------------------
// fused fp32 -> bf16 convert for all 5 inputs (dst segments contiguous in ws)
// ---------------------------------------------------------------------------
__global__ __launch_bounds__(256)
void cvt_all(const float* __restrict__ x,  const float* __restrict__ wq,
             const float* __restrict__ wk, const float* __restrict__ wv,
             const float* __restrict__ wo, u16* __restrict__ dst)
{
  const size_t NB = (size_t)4096 * 4096;
  const size_t KV = (size_t)4096 * 1024;
  const size_t gi = ((size_t)blockIdx.x * 256 + threadIdx.x) * 4;
  const float* src;
  size_t li;
  if (gi < NB)                { src = x;  li = gi; }
  else if (gi < 2 * NB)       { src = wq; li = gi - NB; }
  else if (gi < 2 * NB + KV)  { src = wk; li = gi - 2 * NB; }
  else if (gi < 2 * NB + 2*KV){ src = wv; li = gi - 2 * NB - KV; }
  else                        { src = wo; li = gi - 2 * NB - 2 * KV; }
  const float4 v = *(const float4*)(src + li);
  u16 o[4] = { f2bf(v.x), f2bf(v.y), f2bf(v.z), f2bf(v.w) };
  *(ushort4*)(dst + gi) = *(ushort4*)o;
}

DEV void storec(float* p, float v) { *p = v; }
DEV void storec(u16* p, float v)   { *p = f2bf(v); }

// ---------------------------------------------------------------------------
// 256x256 8-phase GEMM (T2 swizzle + T3/T4 counted vmcnt + T5 setprio).
// Verified round 3. C = A[M,K] * Bt[N,K]^T. 512 threads = 8 waves. BK=64.
// ---------------------------------------------------------------------------
#define BARR  __builtin_amdgcn_s_barrier()
#define LGKM0 asm volatile("s_waitcnt lgkmcnt(0)" ::: "memory")
#define WVM4  asm volatile("s_waitcnt vmcnt(4)" ::: "memory")
#define WVM2  asm volatile("s_waitcnt vmcnt(2)" ::: "memory")
#define WVM0  asm volatile("s_waitcnt vmcnt(0)" ::: "memory")
#define MEMF  asm volatile("" ::: "memory")
#define PRIO1 __builtin_amdgcn_s_setprio(1)
#define PRIO0 __builtin_amdgcn_s_setprio(0)

template <typename TC>
__global__ __launch_bounds__(512, 2)
void gemm_256(const u16* __restrict__ A, const u16* __restrict__ Bt,
              TC* __restrict__ C, int M, int N, int K)
{
  __shared__ u16 lA[2][2][8192];
  __shared__ u16 lB[2][2][8192];

  const int tid  = threadIdx.x;
  const int wid  = tid >> 6;
  const int lane = tid & 63;
  const int quad = lane >> 4;
  const int l16  = lane & 15;
  const int wr   = wid >> 2;    // 0..1
  const int wc   = wid & 3;     // 0..3
  const int r0   = blockIdx.y * 256;
  const int c0   = blockIdx.x * 256;

  const int srow = tid >> 3;                                  // 0..63
  const int scol = (((tid & 7) ^ ((tid >> 3) & 7)) << 3);     // u16 units
  const u16* pA = A  + (size_t)(r0 + srow) * K + scol;
  const u16* pB = Bt + (size_t)(c0 + srow) * K + scol;
  const size_t h64  = (size_t)64 * K;
  const size_t h128 = (size_t)128 * K;

  const int swz = (l16 & 7) << 3;
  const int ko0 = (quad * 8) ^ swz;
  const int ko1 = (32 + quad * 8) ^ swz;

  f4v acc[2][2][4][2];
#pragma unroll
  for (int a = 0; a < 2; ++a)
#pragma unroll
    for (int b = 0; b < 2; ++b)
#pragma unroll
      for (int c = 0; c < 4; ++c)
#pragma unroll
        for (int d = 0; d < 2; ++d) acc[a][b][c][d] = (f4v)0.0f;

  s8v af[4][2], b0f[2][2], b1f[2][2];

#define STG_A(BUF, H, K0) do {                                  \
    const u16* g = pA + (size_t)(H) * h128 + (K0);              \
    load_lds16(g,       &lA[BUF][H][wid * 512]);                \
    load_lds16(g + h64, &lA[BUF][H][wid * 512 + 4096]);         \
  } while (0)
#define STG_B(BUF, H, K0) do {                                  \
    const u16* g = pB + (size_t)(H) * h128 + (K0);              \
    load_lds16(g,       &lB[BUF][H][wid * 512]);                \
    load_lds16(g + h64, &lB[BUF][H][wid * 512 + 4096]);         \
  } while (0)

#define RD_A(BUF, MH) do {                                      \
    _Pragma("unroll")                                           \
    for (int mi = 0; mi < 4; ++mi) {                            \
      const int lr = wr * 64 + mi * 16 + l16;                   \
      af[mi][0] = *(const s8v*)&lA[BUF][MH][lr * 64 + ko0];     \
      af[mi][1] = *(const s8v*)&lA[BUF][MH][lr * 64 + ko1];     \
    } } while (0)
#define RD_B(BUF, NH, DST) do {                                 \
    _Pragma("unroll")                                           \
    for (int ni = 0; ni < 2; ++ni) {                            \
      const int lr = wc * 32 + ni * 16 + l16;                   \
      DST[ni][0] = *(const s8v*)&lB[BUF][NH][lr * 64 + ko0];    \
      DST[ni][1] = *(const s8v*)&lB[BUF][NH][lr * 64 + ko1];    \
    } } while (0)

#define MF(MH, NH, BF) do {                                     \
    _Pragma("unroll")                                           \
    for (int mi = 0; mi < 4; ++mi)                              \
      _Pragma("unroll")                                         \
      for (int ni = 0; ni < 2; ++ni) {                          \
        acc[MH][NH][mi][ni] = mfma16(af[mi][0], BF[ni][0], acc[MH][NH][mi][ni]); \
        acc[MH][NH][mi][ni] = mfma16(af[mi][1], BF[ni][1], acc[MH][NH][mi][ni]); \
      } } while (0)

#define TILE(BUF, KN)                                                     \
  RD_A(BUF, 0); RD_B(BUF, 0, b0f); STG_A(BUF ^ 1, 0, KN);                 \
  BARR; LGKM0; PRIO1; MF(0, 0, b0f); PRIO0; WVM4; BARR;                   \
  RD_B(BUF, 1, b1f); STG_B(BUF ^ 1, 0, KN);                               \
  BARR; LGKM0; PRIO1; MF(0, 1, b1f); PRIO0; WVM4; BARR;                   \
  RD_A(BUF, 1); STG_B(BUF ^ 1, 1, KN);                                    \
  BARR; LGKM0; PRIO1; MF(1, 0, b0f); PRIO0; MEMF; BARR;                   \
  STG_A(BUF ^ 1, 1, KN);                                                  \
  BARR; LGKM0; PRIO1; MF(1, 1, b1f); PRIO0; WVM4; BARR;

#define FTILE(BUF)                                                        \
  RD_A(BUF, 0); RD_B(BUF, 0, b0f);                                        \
  BARR; LGKM0; PRIO1; MF(0, 0, b0f); PRIO0; WVM2; BARR;                   \
  RD_B(BUF, 1, b1f);                                                      \
  BARR; LGKM0; PRIO1; MF(0, 1, b1f); PRIO0; WVM0; BARR;                   \
  RD_A(BUF, 1);                                                           \
  BARR; LGKM0; PRIO1; MF(1, 0, b0f); PRIO0; MEMF; BARR;                   \
  PRIO1; MF(1, 1, b1f); PRIO0;

  STG_A(0, 0, 0); STG_B(0, 0, 0); STG_B(0, 1, 0); STG_A(0, 1, 0);
  WVM4; BARR;

  const int NT = K >> 6;
  for (int kt = 0; kt < NT - 2; kt += 2) {
    const int ka = (kt + 1) << 6;
    const int kb = (kt + 2) << 6;
    TILE(0, ka);
    TILE(1, kb);
  }
  TILE(0, (NT - 1) << 6);
  FTILE(1);

#pragma unroll
  for (int mh = 0; mh < 2; ++mh)
#pragma unroll
    for (int nh = 0; nh < 2; ++nh)
#pragma unroll
      for (int mi = 0; mi < 4; ++mi)
#pragma unroll
        for (int ni = 0; ni < 2; ++ni) {
          const int col = c0 + nh * 128 + wc * 32 + ni * 16 + l16;
#pragma unroll
          for (int reg = 0; reg < 4; ++reg) {
            const int row = r0 + mh * 128 + wr * 64 + mi * 16 + quad * 4 + reg;
            storec(&C[(size_t)row * N + col], acc[mh][nh][mi][ni][reg]);
          }
        }
#undef STG_A
#undef STG_B
#undef RD_A
#undef RD_B
#undef MF
#undef TILE
#undef FTILE
}

// ---------------------------------------------------------------------------
// Fused-conversion GEMM (fallback path; verified earlier).
// ---------------------------------------------------------------------------
DEV void stage8(const float* g, u16* dst) {
  const float4 a = *(const float4*)g;
  const float4 b = *(const float4*)(g + 4);
  u16 t[8] = { f2bf(a.x), f2bf(a.y), f2bf(a.z), f2bf(a.w),
               f2bf(b.x), f2bf(b.y), f2bf(b.z), f2bf(b.w) };
  *(s8v*)dst = *(s8v*)t;
}
DEV void stage8(const u16* g, u16* dst) {
  *(s8v*)dst = *(const s8v*)g;
}

template <typename TA, typename TB, typename TC>
__global__ __launch_bounds__(256)
void gemm_bt_f(const TA* __restrict__ A, const TB* __restrict__ Bt,
               TC* __restrict__ C, int M, int N, int K)
{
  __shared__ u16 lds_a[128 * 32];
  __shared__ u16 lds_b[128 * 32];

  const int tid  = threadIdx.x;
  const int w    = tid >> 6;
  const int lane = tid & 63;
  const int quad = lane >> 4;
  const int l16  = lane & 15;
  const int bm   = blockIdx.y;
  const int bn   = blockIdx.x;
  const int wm   = (w >> 1) * 64;
  const int wn   = (w & 1) * 64;

  const int srow = tid >> 2;
  const int scol = (tid & 3) * 8;

  const TA* ga0 = A  + ((size_t)(bm * 128 + srow)) * K + scol;
  const TB* gb0 = Bt + ((size_t)(bn * 128 + srow)) * K + scol;
  const TA* ga1 = ga0 + (size_t)64 * K;
  const TB* gb1 = gb0 + (size_t)64 * K;

  f4v acc[4][4];
#pragma unroll
  for (int i = 0; i < 4; ++i)
#pragma unroll
    for (int j = 0; j < 4; ++j) acc[i][j] = (f4v)0.0f;

  for (int k0 = 0; k0 < K; k0 += 32) {
    stage8(ga0 + k0, &lds_a[tid * 8]);
    stage8(ga1 + k0, &lds_a[2048 + tid * 8]);
    stage8(gb0 + k0, &lds_b[tid * 8]);
    stage8(gb1 + k0, &lds_b[2048 + tid * 8]);
    __syncthreads();

    s8v af[4], bf[4];
#pragma unroll
    for (int mi = 0; mi < 4; ++mi)
      af[mi] = *(const s8v*)&lds_a[(wm + mi * 16 + l16) * 32 + quad * 8];
#pragma unroll
    for (int ni = 0; ni < 4; ++ni)
      bf[ni] = *(const s8v*)&lds_b[(wn + ni * 16 + l16) * 32 + quad * 8];
#pragma unroll
    for (int mi = 0; mi < 4; ++mi)
#pragma unroll
      for (int ni = 0; ni < 4; ++ni)
        acc[mi][ni] = __builtin_amdgcn_mfma_f32_16x16x32_bf16(af[mi], bf[ni], acc[mi][ni], 0, 0, 0);
    __syncthreads();
  }

#pragma unroll
  for (int mi = 0; mi < 4; ++mi)
#pragma unroll
    for (int ni = 0; ni < 4; ++ni) {
      const int col = bn * 128 + wn + ni * 16 + l16;
#pragma unroll
      for (int reg = 0; reg < 4; ++reg) {
        const int row = bm * 128 + wm + mi * 16 + quad * 4 + reg;
        storec(&C[(size_t)row * N + col], acc[mi][ni][reg]);
      }
    }
}

// ---------------------------------------------------------------------------
// RoPE (interleaved pairs), in-place on bf16 buffers; freqs fp32.
// ---------------------------------------------------------------------------
__global__ __launch_bounds__(256)
void rope_kernel(u16* __restrict__ t, const float* __restrict__ cs,
                 const float* __restrict__ sn, int heads, int rowstride)
{
  const int idx = blockIdx.x * 256 + threadIdx.x;
  const int ppr = heads * 64;
  const int row = idx / ppr;
  const int rem = idx - row * ppr;
  const int head = rem >> 6;
  const int pr   = rem & 63;
  const int pos  = row & 2047;
  const float c = cs[pos * 64 + pr];
  const float s = sn[pos * 64 + pr];
  unsigned int* p = (unsigned int*)(t + (size_t)row * rowstride + head * 128 + pr * 2);
  const unsigned int v = *p;
  const float xr = bf2f((u16)(v & 0xffffu));
  const float xi = bf2f((u16)(v >> 16));
  const u16 o0 = f2bf(xr * c - xi * s);
  const u16 o1 = f2bf(xr * s + xi * c);
  *p = (unsigned int)o0 | ((unsigned int)o1 << 16);
}

// ---------------------------------------------------------------------------
// Flash attention round 7: round-4 pb structure (verified 216us) + T3/T4
// 2-phase counted-vmcnt pipeline:
//  - K staged via global_load_lds into DOUBLE-BUFFERED linear kt[2][64][128]
//    with m201 XOR swizzle (pre-swizzled per-lane global source; ds_read
//    applies chunk ^= (row&7)).
//  - RAW s_barrier + counted vmcnt: next tile's V loads + K DMA stay in
//    flight across the whole compute phase (the old __syncthreads drained
//    vmcnt(0) per tile -- the documented m97 stall).
//  VMEM ledger (4 ops/iter/wave, order V,V,K,K):
//    BARR; vmcnt(2)[V(kb) ready]; write vt; issue V(kb+1); issue K(kb+1);
//    vmcnt(4)[own K(kb) landed, kb+1 in flight]; lgkmcnt(0); BARR; compute.
//  LDS: kt 32KB + vt 18KB + pb 18KB = 68.6KB -> 2 blocks/CU.
// Grid (16, 32, 2), 512 thr = 8 waves x 16 q.
// ---------------------------------------------------------------------------
__global__ __launch_bounds__(512)
void flash_attn128(const u16* __restrict__ xq, const u16* __restrict__ xk,
                   const u16* __restrict__ xv, u16* __restrict__ out, int kvstride)
{
  const int bx  = (int)gridDim.x - 1 - (int)blockIdx.x;  // longest first
  const int h   = blockIdx.y;
  const int b   = blockIdx.z;
  const int kvh = h >> 2;

  const int tid  = threadIdx.x;
  const int w    = tid >> 6;          // 0..7
  const int lane = tid & 63;
  const int quad = lane >> 4;
  const int l16  = lane & 15;

  __shared__ u16 kt[2][64 * 128];     // K dbuf, linear, XOR-swizzled content
  __shared__ u16 vt[128 * 72];        // V^T block [d][kv], stride 72
  __shared__ u16 pb[8][16 * 72];      // per-wave P [q][kv], stride 72

  // Q fragments: q-row = bx*128 + w*16 + l16
  const u16* qp = xq + ((size_t)(b * 2048 + bx * 128 + w * 16 + l16)) * 4096 + h * 128 + quad * 8;
  s8v qf[4];
#pragma unroll
  for (int ks = 0; ks < 4; ++ks) qf[ks] = *(const s8v*)(qp + ks * 32);

  f4v oa[8];
#pragma unroll
  for (int i = 0; i < 8; ++i) oa[i] = (f4v)0.0f;
  float l_part[4] = {0.0f, 0.0f, 0.0f, 0.0f};

  // K DMA staging map: thread covers rows {w*4+(lane>>4), +32}, 16B chunk
  // (lane&15); source col pre-swizzled so linear LDS == swizzled layout.
  const int krow = w * 4 + (lane >> 4);                  // 0..31
  const int ksw  = ((lane & 15) ^ (krow & 7)) * 8;       // u16 src col
  // V staging map (reg-staged, transposed write)
  const int vkv2 = (tid & 31) * 2;      // 0..62
  const int vdg  = tid >> 5;            // 0..15 -> d group of 8

  const u16* kbase = xk + (size_t)(b * 2048) * kvstride + kvh * 128;
  const u16* vbase = xv + (size_t)(b * 2048) * kvstride + kvh * 128;

  const float scale = 0.08838834764831845f;  // 1/sqrt(128)
  const float MFIX  = 8.0f;                  // fixed softmax shift

  const int nkb   = 2 * bx + 2;              // KV tiles for this q-block
  const int qmaxw = bx * 128 + w * 16 + 15;  // wave's max q-pos (tile skip)
  const int swz   = l16 & 7;                 // read-side XOR (row&7 == l16&7)

  // ---- prologue: issue V(0) (2 loads) then K(0) (2 gload_lds)
  s8v vr[2];
  {
    const u16* vg = vbase + (size_t)vkv2 * kvstride + vdg * 8;
    vr[0] = *(const s8v*)(vg);
    vr[1] = *(const s8v*)(vg + kvstride);
    const u16* kg = kbase + (size_t)krow * kvstride + ksw;
    load_lds16(kg, &kt[0][w * 512]);
    load_lds16(kg + (size_t)32 * kvstride, &kt[0][w * 512 + 4096]);
  }

  for (int kb = 0; kb < nkb; ++kb) {
    BARR;                             // all waves done computing kb-1
    WVM2;                             // V(kb) regs ready (2 oldest of 4)
    // ---- write vt (tile kb)
#pragma unroll
    for (int j = 0; j < 8; ++j) {
      const int d = vdg * 8 + j;
      *(unsigned int*)&vt[d * 72 + vkv2] =
          (unsigned int)(u16)vr[0][j] | ((unsigned int)(u16)vr[1][j] << 16);
    }
    // ---- issue next tile: V loads then K DMA (stay in flight over compute)
    if (kb + 1 < nkb) {
      const u16* vg = vbase + (size_t)((kb + 1) * 64 + vkv2) * kvstride + vdg * 8;
      vr[0] = *(const s8v*)(vg);
      vr[1] = *(const s8v*)(vg + kvstride);
      const u16* kg = kbase + (size_t)((kb + 1) * 64 + krow) * kvstride + ksw;
      u16* dst = &kt[(kb + 1) & 1][w * 512];
      load_lds16(kg, dst);
      load_lds16(kg + (size_t)32 * kvstride, dst + 4096);
      WVM4;                           // own K(kb) landed; kb+1's 4 ops fly
    } else {
      WVM0;                           // tail: drain everything
    }
    LGKM0;                            // own vt writes done
    BARR;                             // all K(kb) + vt(kb) visible
    const u16* ktc = &kt[kb & 1][0];

    if (kb * 64 <= qmaxw) {           // wave-uniform: skip fully-masked tiles
      // ---- S = Q K^T (16q x 64kv per wave), swizzled kt read
      f4v sa[4];
#pragma unroll
      for (int nb = 0; nb < 4; ++nb) sa[nb] = (f4v)0.0f;
      __builtin_amdgcn_s_setprio(1);
#pragma unroll
      for (int nb = 0; nb < 4; ++nb)
#pragma unroll
        for (int ks = 0; ks < 4; ++ks) {
          const s8v kf = *(const s8v*)&ktc[(nb * 16 + l16) * 128 + ((ks * 4 + quad) ^ swz) * 8];
          sa[nb] = __builtin_amdgcn_mfma_f32_16x16x32_bf16(qf[ks], kf, sa[nb], 0, 0, 0);
        }
      __builtin_amdgcn_s_setprio(0);

      // ---- fixed-shift softmax numerators; per-lane l partials
#pragma unroll
      for (int nb = 0; nb < 4; ++nb)
#pragma unroll
        for (int reg = 0; reg < 4; ++reg) {
          const int kvg  = kb * 64 + nb * 16 + l16;
          const int qpos = bx * 128 + w * 16 + quad * 4 + reg;
          float p = 0.0f;
          if (kvg <= qpos) p = __expf(fmaf(sa[nb][reg], scale, -MFIX));
          l_part[reg] += p;
          pb[w][(quad * 4 + reg) * 72 + nb * 16 + l16] = f2bf(p);
        }

      // ---- O += P V  (pb per-wave: no barrier, compiler inserts lgkmcnt)
      s8v pf[2];
#pragma unroll
      for (int ks = 0; ks < 2; ++ks)
        pf[ks] = *(const s8v*)&pb[w][l16 * 72 + ks * 32 + quad * 8];
      __builtin_amdgcn_s_setprio(1);
#pragma unroll
      for (int d8 = 0; d8 < 8; ++d8)
#pragma unroll
        for (int ks = 0; ks < 2; ++ks) {
          const s8v vf = *(const s8v*)&vt[(d8 * 16 + l16) * 72 + ks * 32 + quad * 8];
          oa[d8] = __builtin_amdgcn_mfma_f32_16x16x32_bf16(pf[ks], vf, oa[d8], 0, 0, 0);
        }
      __builtin_amdgcn_s_setprio(0);
    }
  }

  // ---- final l reduction across the 16 kv-lanes of each row, then write
#pragma unroll
  for (int reg = 0; reg < 4; ++reg) {
    float l = l_part[reg];
    l += __shfl_xor(l, 1);
    l += __shfl_xor(l, 2);
    l += __shfl_xor(l, 4);
    l += __shfl_xor(l, 8);
    const float inv = 1.0f / l;
    const int row = bx * 128 + w * 16 + quad * 4 + reg;
    u16* op = out + ((size_t)(b * 2048 + row)) * 4096 + h * 128 + l16;
#pragma unroll
    for (int d8 = 0; d8 < 8; ++d8)
      op[d8 * 16] = f2bf(oa[d8][reg] * inv);
  }
}

// ---------------------------------------------------------------------------
extern "C" void kernel_launch(void* const* d_in, const int* in_sizes, int n_in,
                              void* d_out, int out_size, void* d_ws, size_t ws_size,
                              hipStream_t stream)
{
  const float* x  = (const float*)d_in[0];
  const float* fc = (const float*)d_in[2];
  const float* fs = (const float*)d_in[3];
  const float* wq = (const float*)d_in[4];
  const float* wk = (const float*)d_in[5];
  const float* wv = (const float*)d_in[6];
  const float* wo = (const float*)d_in[7];

  const size_t NE_BIG = (size_t)4096 * 4096;
  const size_t NE_KV  = (size_t)4096 * 1024;

  u16* xq = (u16*)d_out;            // Q staged in d_out
  u16* xk = (u16*)d_ws;             // fast path: fused KV [4096][2048]
  u16* xv = xk + NE_KV;             // slow path layout only
  u16* ao = xv + NE_KV;
  u16* xb  = ao + NE_BIG;           // bf16 inputs, contiguous: xb|wqb|wkb|wvb|wob
  u16* wqb = xb  + NE_BIG;
  u16* wkb = wqb + NE_BIG;
  u16* wvb = wkb + NE_KV;
  u16* wob = wvb + NE_KV;

  const size_t need_fast = (size_t)((wob + NE_BIG) - (u16*)d_ws) * sizeof(u16);

  if (ws_size >= need_fast) {
    cvt_all<<<57344, 256, 0, stream>>>(x, wq, wk, wv, wo, xb);
    gemm_256<u16><<<dim3(16, 16), 512, 0, stream>>>(xb, wqb, xq, 4096, 4096, 4096);
    gemm_256<u16><<<dim3(8, 16),  512, 0, stream>>>(xb, wkb, xk, 4096, 2048, 4096);
    rope_kernel<<<32768, 256, 0, stream>>>(xq, fc, fs, 32, 4096);
    rope_kernel<<<8192,  256, 0, stream>>>(xk, fc, fs, 8, 2048);
    flash_attn128<<<dim3(16, 32, 2), 512, 0, stream>>>(xq, xk, xk + 1024, ao, 2048);
    gemm_256<float><<<dim3(16, 16), 512, 0, stream>>>(ao, wob, (float*)d_out, 4096, 4096, 4096);
  } else {
    gemm_bt_f<float, float, u16><<<dim3(32, 32), 256, 0, stream>>>(x, wq, xq, 4096, 4096, 4096);
    gemm_bt_f<float, float, u16><<<dim3(8, 32),  256, 0, stream>>>(x, wk, xk, 4096, 1024, 4096);
    gemm_bt_f<float, float, u16><<<dim3(8, 32),  256, 0, stream>>>(x, wv, xv, 4096, 1024, 4096);
    rope_kernel<<<32768, 256, 0, stream>>>(xq, fc, fs, 32, 4096);
    rope_kernel<<<8192,  256, 0, stream>>>(xk, fc, fs, 8, 1024);
    flash_attn128<<<dim3(16, 32, 2), 512, 0, stream>>>(xq, xk, xv, ao, 1024);
    gemm_bt_f<u16, float, float><<<dim3(32, 32), 256, 0, stream>>>(ao, wo, (float*)d_out, 4096, 4096, 4096);
  }
}